// Round 6
// baseline (782.901 us; speedup 1.0000x reference)
//
#include <hip/hip_runtime.h>
#include <hip/hip_bf16.h>

#define DE 1024
#define DM 64
#define DC 128
#define DX 1152      // DE+DC
#define NB 4
#define NN 4096
#define NT 16384     // NB*NN

typedef _Float16 f16;
typedef _Float16 f16x4 __attribute__((ext_vector_type(4)));
typedef _Float16 f16x8 __attribute__((ext_vector_type(8)));
typedef float f32x4 __attribute__((ext_vector_type(4)));

__device__ __forceinline__ void g2l16(const void* g, void* l) {
  __builtin_amdgcn_global_load_lds(
      (const __attribute__((address_space(1))) unsigned int*)(unsigned long long)g,
      (__attribute__((address_space(3))) unsigned int*)(unsigned int)(unsigned long long)l,
      16, 0, 0);
}

// compile-time region pins only; no memory clobbers, no runtime cost
#define SBAR() do { __builtin_amdgcn_sched_barrier(0);                 \
                    __builtin_amdgcn_s_barrier();                      \
                    __builtin_amdgcn_sched_barrier(0); } while (0)
#define VMWAIT(n) do { __builtin_amdgcn_sched_barrier(0);              \
                       asm volatile("s_waitcnt vmcnt(" #n ")");        \
                       __builtin_amdgcn_sched_barrier(0); } while (0)
#define LGKM0() do { __builtin_amdgcn_sched_barrier(0);                \
                     asm volatile("s_waitcnt lgkmcnt(0)");             \
                     __builtin_amdgcn_sched_barrier(0); } while (0)

// ---------------- prep kernels ----------------
__global__ void build_x_kernel(const float* __restrict__ e, const float* __restrict__ c,
                               f16* __restrict__ Xb) {
  const int total = NT * DX / 4;
  for (int i = blockIdx.x * blockDim.x + threadIdx.x; i < total; i += gridDim.x * blockDim.x) {
    int idx = i * 4;
    int r = idx / DX, col = idx - r * DX;
    float4 v;
    if (col < DE) v = *(const float4*)(e + (long)r * DE + col);
    else          v = *(const float4*)(c + (long)r * DC + (col - DE));
    f16x4 o = { (f16)v.x, (f16)v.y, (f16)v.z, (f16)v.w };
    *(f16x4*)(Xb + (long)idx) = o;
  }
}

__global__ void conv_f16_kernel(const float* __restrict__ in, f16* __restrict__ out, int total4) {
  for (int i = blockIdx.x * blockDim.x + threadIdx.x; i < total4; i += gridDim.x * blockDim.x) {
    float4 v = *(const float4*)(in + (long)i * 4);
    f16x4 o = { (f16)v.x, (f16)v.y, (f16)v.z, (f16)v.w };
    *(f16x4*)(out + (long)i * 4) = o;
  }
}

// in [DX][DE] f32  ->  out [DE][DX] f16
__global__ void transpose_w_kernel(const float* __restrict__ in, f16* __restrict__ out) {
  __shared__ float tile[32][33];
  int c0 = blockIdx.x * 32, r0 = blockIdx.y * 32;
  int x = threadIdx.x, y = threadIdx.y;   // block (32,8)
#pragma unroll
  for (int i = 0; i < 4; ++i)
    tile[y + 8 * i][x] = in[(long)(r0 + y + 8 * i) * DE + (c0 + x)];
  __syncthreads();
#pragma unroll
  for (int i = 0; i < 4; ++i)
    out[(long)(c0 + y + 8 * i) * DX + (r0 + x)] = (f16)tile[x][y + 8 * i];
}

// ---------------- legacy 128^2 GEMM core (mask GEMM, K=64) -----
__device__ __forceinline__ void mm_loop(const f16* __restrict__ A, const f16* __restrict__ B,
                                        int lda, int ldb, int K,
                                        f16* lA, f16* lB, f32x4 (&acc)[4][4]) {
  const int t = threadIdx.x;
  const int lane = t & 63;
  const int wid = t >> 6;
  const int wr = (wid >> 1) * 64, wc = (wid & 1) * 64;
  const int fr = lane & 15, fq = lane >> 4;
  for (int k0 = 0; k0 < K; k0 += 32) {
    __syncthreads();
#pragma unroll
    for (int it = 0; it < 2; ++it) {
      int byteoff = it * 4096 + t * 16;
      int row = byteoff >> 6;
      int ke = (byteoff & 63) >> 1;
      g2l16(A + (long)row * lda + k0 + ke, lA + (byteoff >> 1));
      g2l16(B + (long)row * ldb + k0 + ke, lB + (byteoff >> 1));
    }
    __syncthreads();
    f16x8 af[4], bfr[4];
#pragma unroll
    for (int i = 0; i < 4; ++i) {
      af[i]  = *(const f16x8*)(lA + (wr + i * 16 + fr) * 32 + fq * 8);
      bfr[i] = *(const f16x8*)(lB + (wc + i * 16 + fr) * 32 + fq * 8);
    }
#pragma unroll
    for (int m = 0; m < 4; ++m)
#pragma unroll
      for (int n = 0; n < 4; ++n)
        acc[m][n] = __builtin_amdgcn_mfma_f32_16x16x32_f16(af[m], bfr[n], acc[m][n], 0, 0, 0);
  }
}

// Pmask[b][i][j] = (m_i . m_j) * l_i * l_j / 32   (f16), grid (32,32,4)
__global__ __launch_bounds__(256) void mask_kernel(
    const f16* __restrict__ mb, const float* __restrict__ l, f16* __restrict__ Pm) {
  __shared__ __attribute__((aligned(16))) f16 lA[128 * 32], lB[128 * 32];
  f32x4 acc[4][4];
#pragma unroll
  for (int m = 0; m < 4; ++m)
#pragma unroll
    for (int n = 0; n < 4; ++n) acc[m][n] = (f32x4){0.f, 0.f, 0.f, 0.f};
  const int b = blockIdx.z;
  const int row0 = blockIdx.x * 128, col0 = blockIdx.y * 128;
  mm_loop(mb + (long)(b * NN + row0) * DM, mb + (long)(b * NN + col0) * DM,
          DM, DM, DM, lA, lB, acc);
  const int lane = threadIdx.x & 63, wid = threadIdx.x >> 6;
  const int wr = (wid >> 1) * 64, wc = (wid & 1) * 64;
  const int fr = lane & 15, fq = lane >> 4;
  const float* lb = l + (long)b * NN;
  f16* out = Pm + (long)b * NN * NN;
#pragma unroll
  for (int n = 0; n < 4; ++n) {
    int col = col0 + wc + n * 16 + fr;
    float lc = lb[col] * 0.03125f;
#pragma unroll
    for (int m = 0; m < 4; ++m)
#pragma unroll
      for (int r = 0; r < 4; ++r) {
        int row = row0 + wr + m * 16 + fq * 4 + r;
        out[(long)row * NN + col] = (f16)(acc[m][n][r] * lc * lb[row]);
      }
  }
}

// ---------------- 256x128 GEMM core, BK=32, 4 waves, 48KB LDS -> 2 blocks/CU
// C[256x128] = A[256xK] * B[128xK]^T ; 4 waves (2M x 2N), per-wave 128x64,
// acc[8][4] of 16x16x32 f16 MFMA. LDS rows are 64B (BK=32) -> frag reads and
// linear staging are naturally bank-balanced: NO swizzle anywhere.
// Sync: 2 barriers/K-tile. lgkmcnt(0) before mid-barrier guarantees all
// waves' reads of buf[par] complete before any wave's stage (tt+2 -> same
// buf) can land. vmcnt(6) ledger: prologue stages t0,t1 (12 instr) ->
// vmwait(6) lands t0; each iter stages tt+2 (6 instr) -> vmwait(6) lands
// tt+1 (read next iter). Tail iters: vmwait(0).
__device__ __forceinline__ void gemm4_core(
    const f16* __restrict__ A, long lda,
    const f16* __restrict__ B, long ldb,
    int NTt, char* ldsb, f32x4 (&acc)[8][4]) {
  const int tid = threadIdx.x;          // 0..255
  const int lane = tid & 63, wid = tid >> 6;
  const int wr = wid >> 1, wc = wid & 1;
  const int fr = lane & 15, fq = lane >> 4;

  const f16* srcA = A + (long)(tid >> 2) * lda + (tid & 3) * 8;
  const f16* srcB = B + (long)(tid >> 2) * ldb + (tid & 3) * 8;

  auto stageA = [&](int kt, int par) {   // 16KB tile = 4 instr
    char* base = ldsb + par * 24576;
#pragma unroll
    for (int it = 0; it < 4; ++it)
      g2l16(srcA + (long)(it * 64) * lda + kt * 32, base + it * 4096 + tid * 16);
  };
  auto stageB = [&](int kt, int par) {   // 8KB tile = 2 instr
    char* base = ldsb + par * 24576 + 16384;
#pragma unroll
    for (int it = 0; it < 2; ++it)
      g2l16(srcB + (long)(it * 64) * ldb + kt * 32, base + it * 4096 + tid * 16);
  };

  const int aoff = (wr * 128 + fr) * 64 + fq * 16;   // bytes
  const int boff = (wc * 64 + fr) * 64 + fq * 16;

  auto mma16 = [&](f16x8 (&a4)[4], f16x8 (&b4)[4], int mo) {
    __builtin_amdgcn_s_setprio(1);
#pragma unroll
    for (int m = 0; m < 4; ++m)
#pragma unroll
      for (int n = 0; n < 4; ++n)
        acc[mo + m][n] =
            __builtin_amdgcn_mfma_f32_16x16x32_f16(a4[m], b4[n], acc[mo + m][n], 0, 0, 0);
    __builtin_amdgcn_s_setprio(0);
  };

  // prologue: tiles t0 (buf0) and t1 (buf1)
  stageA(0, 0); stageB(0, 0); stageA(1, 1); stageB(1, 1);
  VMWAIT(6);       // t0's 6 landed; t1's 6 in flight
  SBAR();

  for (int tt = 0; tt < NTt; ++tt) {
    const int par = tt & 1;
    const char* bA = ldsb + par * 24576;
    const char* bB = bA + 16384;
    f16x8 af[4], af2[4], bf[4];
#pragma unroll
    for (int i = 0; i < 4; ++i)
      af[i] = *(const f16x8*)(const void*)(bA + aoff + i * 1024);
#pragma unroll
    for (int n = 0; n < 4; ++n)
      bf[n] = *(const f16x8*)(const void*)(bB + boff + n * 1024);
    mma16(af, bf, 0);                    // rows 0-63 of wave tile
#pragma unroll
    for (int i = 0; i < 4; ++i)          // rows 64-127 (compiler may overlap w/ mma)
      af2[i] = *(const f16x8*)(const void*)(bA + aoff + 4096 + i * 1024);
    LGKM0();                             // my reads of buf[par] done
    SBAR();                              // => ALL waves' reads done; safe to overwrite
    mma16(af2, bf, 4);
    if (tt + 2 < NTt) {
      stageA(tt + 2, par); stageB(tt + 2, par);  // overwrite buf[par]
      VMWAIT(6);                         // tile tt+1 fully landed
    } else {
      VMWAIT(0);                         // tail drain
    }
    SBAR();                              // buf[par^1] (tile tt+1) visible
  }
}

__device__ __forceinline__ void swz_grid(int& bx, int& by, int& bz) {
  int nx = gridDim.x, ny = gridDim.y;
  int flat = blockIdx.x + nx * (blockIdx.y + ny * blockIdx.z);
  int total = nx * ny * gridDim.z;
  int cpx = total >> 3;               // all grids are multiples of 8
  flat = (flat & 7) * cpx + (flat >> 3);
  bx = flat % nx; int r = flat / nx;
  by = r % ny; bz = r / ny;
}

#define ACC_INIT()                                                  \
  f32x4 acc[8][4];                                                  \
  _Pragma("unroll") for (int m_ = 0; m_ < 8; ++m_)                  \
  _Pragma("unroll") for (int n_ = 0; n_ < 4; ++n_)                  \
      acc[m_][n_] = (f32x4){0.f, 0.f, 0.f, 0.f};

#define EPI4_IDX()                                                  \
  const int lane = threadIdx.x & 63, wid = threadIdx.x >> 6;        \
  const int wr = wid >> 1, wc = wid & 1;                            \
  const int fr = lane & 15, fq = lane >> 4;

// q,k projection: M=16384, N=2048 (q|k), K=1152. grid (64,16)
__global__ __launch_bounds__(256, 2) void qk8_kernel(
    const f16* __restrict__ Xb, const f16* __restrict__ Wt,
    const float* __restrict__ bq, const float* __restrict__ bk,
    f16* __restrict__ qb, f16* __restrict__ kb) {
  __shared__ __attribute__((aligned(128))) char ldsb[49152];
  int bx, by, bz; swz_grid(bx, by, bz);
  const int row0 = bx * 256, col0 = by * 128;
  ACC_INIT();
  gemm4_core(Xb + (long)row0 * DX, DX, Wt + (long)col0 * DX, DX, DX / 32, ldsb, acc);
  EPI4_IDX();
  const bool isq = col0 < DE;
  const float* bvec = isq ? bq : bk;
  f16* ob = isq ? qb : kb;
  const int cbase = (isq ? col0 : col0 - DE) + wc * 64;
  const int rbase = row0 + wr * 128;
#pragma unroll
  for (int n = 0; n < 4; ++n) {
    int col = cbase + n * 16 + fr;
    float bb = bvec[col];
#pragma unroll
    for (int m = 0; m < 8; ++m)
#pragma unroll
      for (int j = 0; j < 4; ++j) {
        int row = rbase + m * 16 + fq * 4 + j;
        ob[(long)row * DE + col] = (f16)(acc[m][n][j] + bb);
      }
  }
}

// Vt[d][token]: M=1024 (d), N=16384 (tokens), K=1152. grid (4,128)
__global__ __launch_bounds__(256, 2) void vt8_kernel(
    const f16* __restrict__ WtV, const f16* __restrict__ Xb,
    const float* __restrict__ bv, f16* __restrict__ Vt) {
  __shared__ __attribute__((aligned(128))) char ldsb[49152];
  int bx, by, bz; swz_grid(bx, by, bz);
  const int row0 = bx * 256, col0 = by * 128;
  ACC_INIT();
  gemm4_core(WtV + (long)row0 * DX, DX, Xb + (long)col0 * DX, DX, DX / 32, ldsb, acc);
  EPI4_IDX();
  const int cbase = col0 + wc * 64;
  const int rbase = row0 + wr * 128;
#pragma unroll
  for (int n = 0; n < 4; ++n) {
    int col = cbase + n * 16 + fr;
#pragma unroll
    for (int m = 0; m < 8; ++m)
#pragma unroll
      for (int j = 0; j < 4; ++j) {
        int row = rbase + m * 16 + fq * 4 + j;
        Vt[(long)row * NT + col] = (f16)(acc[m][n][j] + bv[row]);
      }
  }
}

// raw scores per batch: S = q.k (fp32). grid (16,32)
__global__ __launch_bounds__(256, 2) void sc8_kernel(
    const f16* __restrict__ qb_, const f16* __restrict__ kb_, float* __restrict__ S) {
  __shared__ __attribute__((aligned(128))) char ldsb[49152];
  int bx, by, bz; swz_grid(bx, by, bz);
  const int row0 = bx * 256, col0 = by * 128;
  ACC_INIT();
  gemm4_core(qb_ + (long)row0 * DE, DE, kb_ + (long)col0 * DE, DE, DE / 32, ldsb, acc);
  EPI4_IDX();
  const int cbase = col0 + wc * 64;
  const int rbase = row0 + wr * 128;
#pragma unroll
  for (int n = 0; n < 4; ++n) {
    int col = cbase + n * 16 + fr;
#pragma unroll
    for (int m = 0; m < 8; ++m)
#pragma unroll
      for (int j = 0; j < 4; ++j) {
        int row = rbase + m * 16 + fq * 4 + j;
        S[(long)row * NN + col] = acc[m][n][j];
      }
  }
}

// h = P @ V (K=4096); outE = e + h, outH = h. grid (16,8,4)
__global__ __launch_bounds__(256, 2) void pv8_kernel(
    const f16* __restrict__ P, const f16* __restrict__ Vt,
    const float* __restrict__ e, float* __restrict__ outE, float* __restrict__ outH) {
  __shared__ __attribute__((aligned(128))) char ldsb[49152];
  int bx, by, bz; swz_grid(bx, by, bz);
  const int b = bz;
  const int row0 = bx * 256, col0 = by * 128;
  ACC_INIT();
  gemm4_core(P + (long)b * NN * NN + (long)row0 * NN, NN,
             Vt + (long)col0 * NT + (long)b * NN, NT, NN / 32, ldsb, acc);
  EPI4_IDX();
  const int cbase = col0 + wc * 64;
  const int rbase = row0 + wr * 128;
#pragma unroll
  for (int n = 0; n < 4; ++n) {
    int col = cbase + n * 16 + fr;
#pragma unroll
    for (int m = 0; m < 8; ++m)
#pragma unroll
      for (int j = 0; j < 4; ++j) {
        int row = rbase + m * 16 + fq * 4 + j;
        long idx = ((long)b * NN + row) * DE + col;
        float h = acc[m][n][j];
        outE[idx] = e[idx] + h;
        outH[idx] = h;
      }
  }
}

// row softmax with mask: v = S * Pm -> softmax -> P (f16, in-place over Pm)
__global__ __launch_bounds__(256) void softmax_kernel(const float* __restrict__ S,
                                                      const f16* __restrict__ Pm,
                                                      f16* __restrict__ P) {
  __shared__ float red[8];
  const long row = blockIdx.x;
  const float* s = S + row * NN;
  const f16* pmr = Pm + row * NN;
  const int t = threadIdx.x;
  float4 v[4];
  float mx = -3.0e38f;
#pragma unroll
  for (int i = 0; i < 4; ++i) {
    v[i] = *(const float4*)(s + t * 4 + i * 1024);
    f16x4 m4 = *(const f16x4*)(pmr + t * 4 + i * 1024);
    v[i].x *= (float)m4[0]; v[i].y *= (float)m4[1];
    v[i].z *= (float)m4[2]; v[i].w *= (float)m4[3];
    mx = fmaxf(mx, fmaxf(fmaxf(v[i].x, v[i].y), fmaxf(v[i].z, v[i].w)));
  }
#pragma unroll
  for (int o = 32; o; o >>= 1) mx = fmaxf(mx, __shfl_xor(mx, o));
  if ((t & 63) == 0) red[t >> 6] = mx;
  __syncthreads();
  mx = fmaxf(fmaxf(red[0], red[1]), fmaxf(red[2], red[3]));
  float sum = 0.f;
#pragma unroll
  for (int i = 0; i < 4; ++i) {
    v[i].x = __expf(v[i].x - mx); v[i].y = __expf(v[i].y - mx);
    v[i].z = __expf(v[i].z - mx); v[i].w = __expf(v[i].w - mx);
    sum += v[i].x + v[i].y + v[i].z + v[i].w;
  }
#pragma unroll
  for (int o = 32; o; o >>= 1) sum += __shfl_xor(sum, o);
  if ((t & 63) == 0) red[4 + (t >> 6)] = sum;
  __syncthreads();
  float inv = 1.f / (red[4] + red[5] + red[6] + red[7]);
  f16* p = P + row * NN;
#pragma unroll
  for (int i = 0; i < 4; ++i) {
    f16x4 o4 = { (f16)(v[i].x * inv), (f16)(v[i].y * inv),
                 (f16)(v[i].z * inv), (f16)(v[i].w * inv) };
    *(f16x4*)(p + t * 4 + i * 1024) = o4;
  }
}

extern "C" void kernel_launch(void* const* d_in, const int* in_sizes, int n_in,
                              void* d_out, int out_size, void* d_ws, size_t ws_size,
                              hipStream_t stream) {
  const float* e  = (const float*)d_in[0];
  const float* m  = (const float*)d_in[1];
  const float* c  = (const float*)d_in[2];
  const float* l  = (const float*)d_in[3];
  const float* Wq = (const float*)d_in[4];
  const float* bq = (const float*)d_in[5];
  const float* Wk = (const float*)d_in[6];
  const float* bk = (const float*)d_in[7];
  const float* Wv = (const float*)d_in[8];
  const float* bv = (const float*)d_in[9];
  float* outE = (float*)d_out;
  float* outH = outE + (long)NT * DE;

  char* ws = (char*)d_ws;
  size_t off = 0;
  auto alloc = [&](size_t bytes) {
    char* p = ws + off;
    off += (bytes + 255) & ~(size_t)255;
    return p;
  };
  f16* Xb    = (f16*)alloc((size_t)NT * DX * 2);
  f16* WtQK  = (f16*)alloc((size_t)2048 * DX * 2);
  f16* WtV   = (f16*)alloc((size_t)DE * DX * 2);
  f16* qb    = (f16*)alloc((size_t)NT * DE * 2);
  f16* kb    = (f16*)alloc((size_t)NT * DE * 2);
  f16* Vt    = (f16*)alloc((size_t)DE * NT * 2);
  f16* mb    = (f16*)alloc((size_t)NT * DM * 2);
  float* S   = (float*)alloc((size_t)NN * NN * 4);
  f16* P     = (f16*)alloc((size_t)NB * NN * NN * 2);  // Pmask aliases P (consumed in-place)
  if (off > ws_size) return;

  build_x_kernel<<<2048, 256, 0, stream>>>(e, c, Xb);
  conv_f16_kernel<<<512, 256, 0, stream>>>(m, mb, NT * DM / 4);
  transpose_w_kernel<<<dim3(32, 36), dim3(32, 8), 0, stream>>>(Wq, WtQK);
  transpose_w_kernel<<<dim3(32, 36), dim3(32, 8), 0, stream>>>(Wk, WtQK + (size_t)DE * DX);
  transpose_w_kernel<<<dim3(32, 36), dim3(32, 8), 0, stream>>>(Wv, WtV);
  mask_kernel<<<dim3(32, 32, NB), 256, 0, stream>>>(mb, l, P);
  qk8_kernel<<<dim3(64, 16), 256, 0, stream>>>(Xb, WtQK, bq, bk, qb, kb);
  vt8_kernel<<<dim3(4, 128), 256, 0, stream>>>(WtV, Xb, bv, Vt);
  for (int b = 0; b < NB; ++b) {
    sc8_kernel<<<dim3(16, 32), 256, 0, stream>>>(
        qb + (size_t)b * NN * DE, kb + (size_t)b * NN * DE, S);
    softmax_kernel<<<NN, 256, 0, stream>>>(S, P + (size_t)b * NN * NN, P + (size_t)b * NN * NN);
  }
  pv8_kernel<<<dim3(16, 8, NB), 256, 0, stream>>>(P, Vt, e, outE, outH);
}